// Round 1
// baseline (211.095 us; speedup 1.0000x reference)
//
#include <hip/hip_runtime.h>
#include <math.h>
#include <stdint.h>

typedef _Float16 half8 __attribute__((ext_vector_type(8)));
typedef float floatx4 __attribute__((ext_vector_type(4)));

#define NTOK   16384
#define DIM    2048
#define NEXP   64
#define TPB    16                  // tokens per block
#define NBLK   (NTOK / TPB)        // 1024 blocks
#define NCHW   8                   // chunks per wave (4-way K-split, 64 floats/chunk)
#define WSW_H8 16384               // half8 slots per split
#define WSW_BYTES (2 * WSW_H8 * 16)

// LDS: per-wave private A double-buffer: 4 waves x 2 bufs x 4096 B = 32 KB,
// plus K-split reduction buffer red[4][16][68] f32 = 17408 B. Total 50176 B
// -> 3 blocks/CU (150 KB < 160 KB), 12 waves/CU.
#define ABUF_BYTES 32768
#define RED_STRIDE 68              // 64 + 4 pad: 2-way LDS bank aliasing only (free)
#define RED_F      (4 * 16 * RED_STRIDE)

// ---- prep: split W (fp32) into f16 hi + scaled-lo (2^11), B-fragment order:
// slot(sg,tg,lane) = (sg*4+tg)*64+lane holds W[tg*16+(lane&15)][sg*32+(lane>>4)*8 + 0..7]
__global__ void wprep_kernel(const float* __restrict__ W, _Float16* __restrict__ wsw) {
    const int id   = blockIdx.x * blockDim.x + threadIdx.x; // 0..16383
    const int lane = id & 63;
    const int tg   = (id >> 6) & 3;
    const int sg   = id >> 8;                               // 0..63
    const int e    = tg * 16 + (lane & 15);
    const int k    = sg * 32 + (lane >> 4) * 8;
    const float* src = W + (size_t)e * DIM + k;
    half8 h, l;
#pragma unroll
    for (int j = 0; j < 8; j++) {
        const float v  = src[j];
        const _Float16 hh = (_Float16)v;
        h[j] = hh;
        l[j] = (_Float16)((v - (float)hh) * 2048.0f);
    }
    const size_t slot = (size_t)(sg * 4 + tg) * 64 + lane;
    ((half8*)wsw)[slot]          = h;
    ((half8*)wsw)[WSW_H8 + slot] = l;
}

__device__ __forceinline__ void split_a(const float4& v0, const float4& v1,
                                        half8& hi, half8& lo) {
    const float av[8] = {v0.x, v0.y, v0.z, v0.w, v1.x, v1.y, v1.z, v1.w};
#pragma unroll
    for (int j = 0; j < 8; j++) {
        const _Float16 hh = (_Float16)av[j];
        hi[j] = hh;
        lo[j] = (_Float16)((av[j] - (float)hh) * 2048.0f);
    }
}

// async global->LDS DMA, 16 B/lane. LDS dest = WAVE-UNIFORM base (HW appends lane*16).
__device__ __forceinline__ void dma16(const void* g, const char* l) {
    __builtin_amdgcn_global_load_lds(
        (const __attribute__((address_space(1))) unsigned int*)(uintptr_t)g,
        (__attribute__((address_space(3))) unsigned int*)(uintptr_t)l,
        16, 0, 0);
}

template <bool USE_WS> struct BFrag;
template <> struct BFrag<true>  { half8  h[2][4]; half8 l[2][4]; };
template <> struct BFrag<false> { float4 a[2][4][2]; };

// B loads: exactly 16 VMEM ops per chunk in BOTH variants (vmcnt accounting relies on it).
template <bool USE_WS>
__device__ __forceinline__ void load_b(BFrag<USE_WS>& bf, const half8* wb,
                                       const float* Wb, int cc) {
    if constexpr (USE_WS) {
#pragma unroll
        for (int s = 0; s < 2; s++)
#pragma unroll
            for (int t = 0; t < 4; t++) {
                const size_t o = (size_t)(cc * 8 + s * 4 + t) * 64;
                bf.h[s][t] = wb[o];
                bf.l[s][t] = wb[o + WSW_H8];
            }
    } else {
#pragma unroll
        for (int s = 0; s < 2; s++)
#pragma unroll
            for (int t = 0; t < 4; t++) {
                const float* wr = Wb + (size_t)(t * 16) * DIM + cc * 64 + s * 32;
                bf.a[s][t][0] = *(const float4*)wr;
                bf.a[s][t][1] = *(const float4*)(wr + 4);
            }
    }
}

// Barrier-free main loop. Per-wave chronology (regions sealed by asm memory clobbers):
//   prologue: dmaA(0) | fence | B(0), dmaA(1)
//   iter c:   WAIT_A (vmcnt: B(c)16 + dmaA(c+1)4 = 20 newer than dmaA(c); 16 at c=7)
//             4x ds_read A frags ; s_waitcnt lgkmcnt(0)   (frags in regs, buffer reusable)
//             issue B(c+1) [16 loads] ; issue dmaA(c+2) [4, same buf as current reads]
//             split + 24 MFMA on B(c)  (compiler emits counted vmcnt leaving the 20 new ops)
// Under-wait is impossible: the 20 ops are guaranteed newer than dmaA(c); extra ops
// (e.g. scratch) only grow the newer set -> waits become stricter, never looser.
template <bool USE_WS>
__global__ __launch_bounds__(256, 3)
void gating_kernel(const float* __restrict__ x, const float* __restrict__ W,
                   const _Float16* __restrict__ wsw, const float* __restrict__ bias,
                   float* __restrict__ out)
{
    __shared__ char  abuf[ABUF_BYTES];
    __shared__ float red[RED_F];

    const int tid  = threadIdx.x;
    const int lane = tid & 63;
    const int ks   = tid >> 6;          // K-split index 0..3 (wave id)
    const int col  = lane & 15;
    const int quad = lane >> 4;
    const int tok0 = blockIdx.x * TPB;

    // ---- A DMA sources: instr i covers rows i*4..i*4+3 (256 B each).
    // Gather-side XOR swizzle within 128 B so frag ds_reads land on distinct banks.
    const float* gA[4];
#pragma unroll
    for (int i = 0; i < 4; i++) {
        const int row = i * 4 + quad;
        const int pz  = col;
        const int gp  = (pz & 8) | ((pz & 7) ^ (row & 7));
        gA[i] = x + (size_t)(tok0 + row) * DIM + ks * (NCHW * 64) + gp * 4;
    }
    char* const ab = abuf + ks * 8192;                    // wave-private 2x4KB
    const half8* wb = (const half8*)wsw + (size_t)ks * 4096 + lane;
    const float* Wb = W + (size_t)col * DIM + ks * (NCHW * 64) + quad * 8;

    floatx4 accm[4] = {{0,0,0,0},{0,0,0,0},{0,0,0,0},{0,0,0,0}};
    floatx4 accl[4] = {{0,0,0,0},{0,0,0,0},{0,0,0,0},{0,0,0,0}};

    // prologue
#pragma unroll
    for (int i = 0; i < 4; i++) dma16(gA[i], ab + i * 1024);
    asm volatile("" ::: "memory");     // dmaA(0) stays oldest-4 in the VMEM queue
    BFrag<USE_WS> bc;
    load_b<USE_WS>(bc, wb, Wb, 0);
#pragma unroll
    for (int i = 0; i < 4; i++) dma16(gA[i] + 64, ab + 4096 + i * 1024);

#pragma unroll
    for (int cc = 0; cc < NCHW; ++cc) {
        if (cc == NCHW - 1) asm volatile("s_waitcnt vmcnt(16)" ::: "memory");
        else                asm volatile("s_waitcnt vmcnt(20)" ::: "memory");
        const char* Ab = ab + (cc & 1) * 4096;
        float4 v0[2], v1[2];
#pragma unroll
        for (int s = 0; s < 2; s++) {
            v0[s] = *(const float4*)(Ab + col * 256 + (8 * s + ((2 * quad + 0) ^ (col & 7))) * 16);
            v1[s] = *(const float4*)(Ab + col * 256 + (8 * s + ((2 * quad + 1) ^ (col & 7))) * 16);
        }
        asm volatile("s_waitcnt lgkmcnt(0)" ::: "memory");   // reads done -> buffer reusable
        BFrag<USE_WS> bn;
        if (cc + 1 < NCHW) load_b<USE_WS>(bn, wb, Wb, cc + 1);
        if (cc + 2 < NCHW) {
#pragma unroll
            for (int i = 0; i < 4; i++)
                dma16(gA[i] + (size_t)(cc + 2) * 64, ab + (cc & 1) * 4096 + i * 1024);
        }
#pragma unroll
        for (int s = 0; s < 2; s++) {
            half8 ah, al;
            split_a(v0[s], v1[s], ah, al);
#pragma unroll
            for (int t = 0; t < 4; t++) {
                half8 bh, bl;
                if constexpr (USE_WS) {
                    bh = bc.h[s][t];
                    bl = bc.l[s][t];
                } else {
                    split_a(bc.a[s][t][0], bc.a[s][t][1], bh, bl);
                }
                accm[t] = __builtin_amdgcn_mfma_f32_16x16x32_f16(ah, bh, accm[t], 0, 0, 0);
                accl[t] = __builtin_amdgcn_mfma_f32_16x16x32_f16(ah, bl, accl[t], 0, 0, 0);
                accl[t] = __builtin_amdgcn_mfma_f32_16x16x32_f16(al, bh, accl[t], 0, 0, 0);
            }
        }
        if (cc + 1 < NCHW) bc = bn;
    }

    // ---- K-split reduction: wave ks writes its partial [16 tok][64 exp]
    const float inv = 1.0f / 2048.0f;
#pragma unroll
    for (int t = 0; t < 4; t++)
#pragma unroll
        for (int r = 0; r < 4; r++)   // C/D: row = quad*4+r (token), col = lane&15 (expert)
            red[(ks * 16 + quad * 4 + r) * RED_STRIDE + t * 16 + col] =
                accm[t][r] + accl[t][r] * inv;
    __syncthreads();

    if (tid < TPB) {
        const int tk = tid;
        float v0 = -INFINITY, v1 = -INFINITY;
        int   i0 = 0, i1 = 0;
        for (int e = 0; e < NEXP; e++) {
            const float v = red[(0 * 16 + tk) * RED_STRIDE + e]
                          + red[(1 * 16 + tk) * RED_STRIDE + e]
                          + red[(2 * 16 + tk) * RED_STRIDE + e]
                          + red[(3 * 16 + tk) * RED_STRIDE + e] + bias[e];
            if (v > v0)      { v1 = v0; i1 = i0; v0 = v; i0 = e; }
            else if (v > v1) { v1 = v; i1 = e; }
        }
        const float e1 = expf(v1 - v0);   // v1 <= v0: stable
        const float sden = 1.f + e1;
        const int   g  = tok0 + tk;
        out[2 * g + 0] = 1.f / sden;
        out[2 * g + 1] = e1 / sden;
        out[2 * NTOK + 2 * g + 0] = (float)i0;
        out[2 * NTOK + 2 * g + 1] = (float)i1;
    }
}

extern "C" void kernel_launch(void* const* d_in, const int* in_sizes, int n_in,
                              void* d_out, int out_size, void* d_ws, size_t ws_size,
                              hipStream_t stream) {
    const float* x    = (const float*)d_in[0];
    const float* W    = (const float*)d_in[1];
    const float* bias = (const float*)d_in[2];
    float*       out  = (float*)d_out;
    _Float16*    wsw  = (_Float16*)d_ws;

    if (ws_size >= (size_t)WSW_BYTES) {
        hipLaunchKernelGGL(wprep_kernel, dim3(64), dim3(256), 0, stream, W, wsw);
        hipLaunchKernelGGL((gating_kernel<true>), dim3(NBLK), dim3(256), 0, stream,
                           x, W, wsw, bias, out);
    } else {
        hipLaunchKernelGGL((gating_kernel<false>), dim3(NBLK), dim3(256), 0, stream,
                           x, W, wsw, bias, out);
    }
}